// Round 1
// baseline (3397.754 us; speedup 1.0000x reference)
//
#include <hip/hip_runtime.h>

#define D   256
#define WR  129          // D/2 + 1
#define B   64
static constexpr long PL = (long)D * D * WR;   // one output plane: 8,454,144 floats

// ---------------------------------------------------------------------------
// Kernel 1: per-row real DFT (rfft along x). One block per (b, y) row.
// out F1[b, y, k] for k = 0..128.
// ---------------------------------------------------------------------------
__global__ void __launch_bounds__(256) row_rfft_kernel(const float* __restrict__ imgs,
                                                       float2* __restrict__ F1) {
    const int row = blockIdx.x;            // b*D + y
    const int t   = threadIdx.x;           // 0..255
    __shared__ float xr[D];
    __shared__ float twc[D];
    __shared__ float tws[D];

    xr[t] = imgs[(size_t)row * D + t];
    float s, c;
    // w[m] = exp(-2*pi*i*m/256) -> angle/pi = -m/128 (exact fp32 argument)
    sincospif(-(float)t * (1.0f / 128.0f), &s, &c);
    twc[t] = c; tws[t] = s;
    __syncthreads();

    if (t < WR) {
        float re = 0.f, im = 0.f;
        #pragma unroll 4
        for (int n = 0; n < D; ++n) {
            const int m = (t * n) & (D - 1);
            const float v = xr[n];                // LDS broadcast (free)
            re = fmaf(v, twc[m], re);
            im = fmaf(v, tws[m], im);
        }
        F1[(size_t)row * WR + t] = make_float2(re, im);
    }
}

// ---------------------------------------------------------------------------
// Kernel 2: per-column complex DFT along y (in place), fftshift along y,
// and fused per-particle phase shift. One block per (b, x) column.
// ---------------------------------------------------------------------------
__global__ void __launch_bounds__(256) col_fft_phase_kernel(float2* F1,
                                                            const float* __restrict__ hwShiftAngs) {
    const int col = blockIdx.x;            // b*WR + x
    const int b   = col / WR;
    const int x   = col - b * WR;
    const int t   = threadIdx.x;           // output frequency k (pre-shift)
    __shared__ float2 xin[D];
    __shared__ float  twc[D];
    __shared__ float  tws[D];

    xin[t] = F1[((size_t)b * D + t) * WR + x];
    float s, c;
    sincospif(-(float)t * (1.0f / 128.0f), &s, &c);
    twc[t] = c; tws[t] = s;
    __syncthreads();

    float re = 0.f, im = 0.f;
    #pragma unroll 4
    for (int y = 0; y < D; ++y) {
        const int m = (t * y) & (D - 1);
        const float2 v = xin[y];                 // broadcast
        const float wc = twc[m], ws = tws[m];
        re += v.x * wc - v.y * ws;
        im += v.x * ws + v.y * wc;
    }

    // fftshift along y: input freq index t lands at shifted row h
    const int   h  = (t + D / 2) & (D - 1);
    const float ky = (float)(h - D / 2);
    const float sy = hwShiftAngs[b * 2 + 0];
    const float sx = hwShiftAngs[b * 2 + 1];
    // phase = exp(-2*pi*i*(ky*sy + kx*sx)/D); sincospif arg = angle/pi
    const float ph = -2.0f * (ky * sy + (float)x * sx) * (1.0f / (float)D);
    float ps, pc;
    sincospif(ph, &ps, &pc);
    const float ore = re * pc - im * ps;
    const float oim = re * ps + im * pc;
    F1[((size_t)b * D + h) * WR + x] = make_float2(ore, oim);
}

// ---------------------------------------------------------------------------
// Kernel 3: rotate central slice, Hermitian fold, trilinear scatter-add.
// One thread per (b, h, x) frequency sample.
// out layout: [4, D, D, WR] = {num.re, num.im, wvol, cvol}
// ---------------------------------------------------------------------------
__global__ void __launch_bounds__(256) scatter_kernel(const float2* __restrict__ F,
                                                      const float* __restrict__ ctf,
                                                      const float* __restrict__ rotMats,
                                                      float* __restrict__ out) {
    const int idx = blockIdx.x * 256 + threadIdx.x;   // < B*D*WR = 2,113,536
    const int x   = idx % WR;
    const int tmp = idx / WR;
    const int h   = tmp & (D - 1);
    const int b   = tmp >> 8;

    const float ky = (float)(h - D / 2);
    const float kx = (float)x;

    const float* R = rotMats + b * 9;       // row-major 3x3, rows are z,y,x of output
    float rz = R[1] * ky + R[2] * kx;       // z-column of coords is 0
    float ry = R[4] * ky + R[5] * kx;
    float rx = R[7] * ky + R[8] * kx;

    const float2 f  = F[idx];
    const float  cf = ctf[idx];
    float vre = cf * f.x;
    float vim = cf * f.y;
    if (rx < 0.f) {                          // Hermitian fold
        rz = -rz; ry = -ry; rx = -rx;
        vim = -vim;
    }

    const float zc = rz + (float)(D / 2);
    const float yc = ry + (float)(D / 2);
    const float xc = rx;
    const float z0f = floorf(zc), y0f = floorf(yc), x0f = floorf(xc);
    const float fz = zc - z0f, fy = yc - y0f, fx = xc - x0f;
    const int z0 = (int)z0f, y0 = (int)y0f, x0 = (int)x0f;
    const float csq = cf * cf;

    #pragma unroll
    for (int dz = 0; dz < 2; ++dz) {
        const int zi = z0 + dz;
        if (zi < 0 || zi >= D) continue;
        const float wz = dz ? fz : 1.0f - fz;
        #pragma unroll
        for (int dy = 0; dy < 2; ++dy) {
            const int yi = y0 + dy;
            if (yi < 0 || yi >= D) continue;
            const float wy = dy ? fy : 1.0f - fy;
            #pragma unroll
            for (int dx = 0; dx < 2; ++dx) {
                const int xi = x0 + dx;
                if (xi < 0 || xi >= WR) continue;
                const float wx = dx ? fx : 1.0f - fx;
                const float w = wz * wy * wx;
                const long  o = (long)zi * (D * WR) + (long)yi * WR + xi;
                atomicAdd(out + o,          w * vre);
                atomicAdd(out + PL + o,     w * vim);
                atomicAdd(out + 2 * PL + o, w);
                atomicAdd(out + 3 * PL + o, w * csq);
            }
        }
    }
}

// ---------------------------------------------------------------------------
extern "C" void kernel_launch(void* const* d_in, const int* in_sizes, int n_in,
                              void* d_out, int out_size, void* d_ws, size_t ws_size,
                              hipStream_t stream) {
    const float* imgs    = (const float*)d_in[0];   // [B, D, D]
    const float* ctf     = (const float*)d_in[1];   // [B, D, WR]
    const float* rotMats = (const float*)d_in[2];   // [B, 3, 3]
    const float* hw      = (const float*)d_in[3];   // [B, 2]
    float*  out = (float*)d_out;                    // [4, D, D, WR]
    float2* F1  = (float2*)d_ws;                    // [B, D, WR] complex scratch (16.9 MB)

    hipMemsetAsync(out, 0, (size_t)out_size * sizeof(float), stream);

    row_rfft_kernel<<<B * D, 256, 0, stream>>>(imgs, F1);
    col_fft_phase_kernel<<<B * WR, 256, 0, stream>>>(F1, hw);
    scatter_kernel<<<(B * D * WR) / 256, 256, 0, stream>>>(F1, ctf, rotMats, out);
}

// Round 2
// 1168.867 us; speedup vs baseline: 2.9069x; 2.9069x over previous
//
#include <hip/hip_runtime.h>

#define D   256
#define WR  129          // D/2 + 1
#define B   64
static constexpr long PL = (long)D * D * WR;   // one output plane: 8,454,144 floats
#define SQRT3 1.7320509f

// ---------------------------------------------------------------------------
// Kernel 1: per-row real DFT (rfft along x). One block per (b, y) row.
// out F1[b, y, k] for k = 0..128.
// ---------------------------------------------------------------------------
__global__ void __launch_bounds__(256) row_rfft_kernel(const float* __restrict__ imgs,
                                                       float2* __restrict__ F1) {
    const int row = blockIdx.x;            // b*D + y
    const int t   = threadIdx.x;           // 0..255
    __shared__ float xr[D];
    __shared__ float twc[D];
    __shared__ float tws[D];

    xr[t] = imgs[(size_t)row * D + t];
    float s, c;
    // w[m] = exp(-2*pi*i*m/256) -> angle/pi = -m/128 (exact fp32 argument)
    sincospif(-(float)t * (1.0f / 128.0f), &s, &c);
    twc[t] = c; tws[t] = s;
    __syncthreads();

    if (t < WR) {
        float re = 0.f, im = 0.f;
        #pragma unroll 4
        for (int n = 0; n < D; ++n) {
            const int m = (t * n) & (D - 1);
            const float v = xr[n];                // LDS broadcast (free)
            re = fmaf(v, twc[m], re);
            im = fmaf(v, tws[m], im);
        }
        F1[(size_t)row * WR + t] = make_float2(re, im);
    }
}

// ---------------------------------------------------------------------------
// Kernel 2: per-column complex DFT along y, fftshift along y, fused
// per-particle phase shift, and fused CTF pre-multiplication.
// Writes F4[b,h,x] = (cf*re, cf*im, cf*cf, 0). One block per (b, x) column.
// ---------------------------------------------------------------------------
__global__ void __launch_bounds__(256) col_fft_phase_kernel(const float2* __restrict__ F1,
                                                            const float* __restrict__ ctf,
                                                            const float* __restrict__ hwShiftAngs,
                                                            float4* __restrict__ F4) {
    const int col = blockIdx.x;            // b*WR + x
    const int b   = col / WR;
    const int x   = col - b * WR;
    const int t   = threadIdx.x;           // output frequency k (pre-shift)
    __shared__ float2 xin[D];
    __shared__ float  twc[D];
    __shared__ float  tws[D];

    xin[t] = F1[((size_t)b * D + t) * WR + x];
    float s, c;
    sincospif(-(float)t * (1.0f / 128.0f), &s, &c);
    twc[t] = c; tws[t] = s;
    __syncthreads();

    float re = 0.f, im = 0.f;
    #pragma unroll 4
    for (int y = 0; y < D; ++y) {
        const int m = (t * y) & (D - 1);
        const float2 v = xin[y];                 // broadcast
        const float wc = twc[m], ws = tws[m];
        re += v.x * wc - v.y * ws;
        im += v.x * ws + v.y * wc;
    }

    // fftshift along y: input freq index t lands at shifted row h
    const int   h  = (t + D / 2) & (D - 1);
    const float ky = (float)(h - D / 2);
    const float sy = hwShiftAngs[b * 2 + 0];
    const float sx = hwShiftAngs[b * 2 + 1];
    // phase = exp(-2*pi*i*(ky*sy + kx*sx)/D); sincospif arg = angle/pi
    const float ph = -2.0f * (ky * sy + (float)x * sx) * (1.0f / (float)D);
    float ps, pc;
    sincospif(ph, &ps, &pc);
    const float ore = re * pc - im * ps;
    const float oim = re * ps + im * pc;

    const size_t o = (size_t)(b * D + h) * WR + x;
    const float  cf = ctf[o];
    F4[o] = make_float4(cf * ore, cf * oim, cf * cf, 0.f);
}

// ---------------------------------------------------------------------------
// Kernel 3: GATHER. One thread per output voxel (z,y,x). For each particle,
// compute slice-frame coords q = R^T v'; samples can only touch this voxel
// if qz^2 < 3 and (ky,kx) within sqrt(3) of f*(qy,qx) for fold f=+-1.
// Enumerate the <=4x4 candidate window per fold, apply the exact fold rule
// (rx = R[7]*ky + R[8]*kx < 0) and the trilinear |delta|<1 test.
// Zero atomics; each voxel writes its 4 outputs once.
// ---------------------------------------------------------------------------
__global__ void __launch_bounds__(256) gather_kernel(const float4* __restrict__ F4,
                                                     const float* __restrict__ rotMats,
                                                     float* __restrict__ out) {
    __shared__ float Rs[B * 12];   // per particle: colz(R0,R3,R6)@0, coly(R1,R4,R7)@4, colx(R2,R5,R8)@8
    for (int i = threadIdx.x; i < B * 9; i += 256) {
        const int b = i / 9, k = i - b * 9;
        const int row = k / 3, colc = k - row * 3;
        Rs[b * 12 + colc * 4 + row] = rotMats[i];
    }
    __syncthreads();

    const int idx = blockIdx.x * 256 + threadIdx.x;   // < D*D*WR
    const int x   = idx % WR;
    const int t   = idx / WR;
    const int y   = t & (D - 1);
    const int z   = t >> 8;
    const float vz = (float)(z - D / 2);
    const float vy = (float)(y - D / 2);
    const float vx = (float)x;

    float nre = 0.f, nim = 0.f, wv = 0.f, cv = 0.f;

    for (int b = 0; b < B; ++b) {
        const float* Rb = &Rs[b * 12];
        const float qz = Rb[0] * vz + Rb[1] * vy + Rb[2] * vx;
        if (qz * qz >= 3.0f) continue;
        const float R1 = Rb[4], R4 = Rb[5], R7 = Rb[6];
        const float R2 = Rb[8], R5 = Rb[9], R8 = Rb[10];
        const float qy = R1 * vz + R4 * vy + R7 * vx;
        const float qx = R2 * vz + R5 * vy + R8 * vx;

        #pragma unroll
        for (int fi = 0; fi < 2; ++fi) {
            const float fs = fi ? -1.f : 1.f;
            const float ty = fi ? -qy : qy;
            const float tx = fi ? -qx : qx;
            int ky0 = (int)ceilf(ty - SQRT3);  ky0 = max(ky0, -D / 2);
            int ky1 = (int)floorf(ty + SQRT3); ky1 = min(ky1, D / 2 - 1);
            int kx0 = (int)ceilf(tx - SQRT3);  kx0 = max(kx0, 0);
            int kx1 = (int)floorf(tx + SQRT3); kx1 = min(kx1, WR - 1);
            if (ky0 > ky1 || kx0 > kx1) continue;

            for (int ky = ky0; ky <= ky1; ++ky) {
                const float kyf = (float)ky;
                const float sz = R1 * kyf;
                const float sy = R4 * kyf;
                const float sx = R7 * kyf;     // R7*ky (partial rx)
                const int rowbase = (b * D + (ky + D / 2)) * WR;
                for (int kx = kx0; kx <= kx1; ++kx) {
                    const float kxf = (float)kx;
                    const float rx = fmaf(R8, kxf, sx);      // R[7]*ky + R[8]*kx (matches scatter)
                    if ((rx < 0.f) != (fi == 1)) continue;   // fold membership
                    const float dz_ = fs * fmaf(R2, kxf, sz) - vz;
                    const float az  = fabsf(dz_); if (az >= 1.f) continue;
                    const float dy_ = fs * fmaf(R5, kxf, sy) - vy;
                    const float ay  = fabsf(dy_); if (ay >= 1.f) continue;
                    const float dx_ = fs * rx - vx;
                    const float ax  = fabsf(dx_); if (ax >= 1.f) continue;
                    const float w = (1.f - az) * (1.f - ay) * (1.f - ax);
                    const float4 v = F4[rowbase + kx];
                    nre = fmaf(w, v.x, nre);
                    nim = fmaf(w, fi ? -v.y : v.y, nim);
                    wv += w;
                    cv  = fmaf(w, v.z, cv);
                }
            }
        }
    }

    out[idx]          = nre;
    out[PL + idx]     = nim;
    out[2 * PL + idx] = wv;
    out[3 * PL + idx] = cv;
}

// ---------------------------------------------------------------------------
extern "C" void kernel_launch(void* const* d_in, const int* in_sizes, int n_in,
                              void* d_out, int out_size, void* d_ws, size_t ws_size,
                              hipStream_t stream) {
    const float* imgs    = (const float*)d_in[0];   // [B, D, D]
    const float* ctf     = (const float*)d_in[1];   // [B, D, WR]
    const float* rotMats = (const float*)d_in[2];   // [B, 3, 3]
    const float* hw      = (const float*)d_in[3];   // [B, 2]
    float* out = (float*)d_out;                     // [4, D, D, WR]

    float2* F1 = (float2*)d_ws;                                   // [B,D,WR] complex (16.9 MB)
    float4* F4 = (float4*)((char*)d_ws + (size_t)B * D * WR * 8); // [B,D,WR] float4 (33.8 MB)

    row_rfft_kernel<<<B * D, 256, 0, stream>>>(imgs, F1);
    col_fft_phase_kernel<<<B * WR, 256, 0, stream>>>(F1, ctf, hw, F4);
    gather_kernel<<<(int)(PL / 256), 256, 0, stream>>>(F4, rotMats, out);
}

// Round 3
// 741.468 us; speedup vs baseline: 4.5825x; 1.5764x over previous
//
#include <hip/hip_runtime.h>

#define D   256
#define WR  129          // D/2 + 1
#define B   64
static constexpr long PL = (long)D * D * WR;   // one output plane: 8,454,144 floats
#define SQRT3 1.7320509f

// ---------------------------------------------------------------------------
// Kernel 1: per-row real DFT (rfft along x). One block per (b, y) row.
// ---------------------------------------------------------------------------
__global__ void __launch_bounds__(256) row_rfft_kernel(const float* __restrict__ imgs,
                                                       float2* __restrict__ F1) {
    const int row = blockIdx.x;            // b*D + y
    const int t   = threadIdx.x;           // 0..255
    __shared__ float  xr[D];
    __shared__ float2 tw[D];

    xr[t] = imgs[(size_t)row * D + t];
    float s, c;
    sincospif(-(float)t * (1.0f / 128.0f), &s, &c);  // exp(-2pi i t/256)
    tw[t] = make_float2(c, s);
    __syncthreads();

    if (t < WR) {
        float re = 0.f, im = 0.f;
        #pragma unroll 4
        for (int n = 0; n < D; ++n) {
            const int m = (t * n) & (D - 1);
            const float  v = xr[n];               // LDS broadcast
            const float2 w = tw[m];
            re = fmaf(v, w.x, re);
            im = fmaf(v, w.y, im);
        }
        F1[(size_t)row * WR + t] = make_float2(re, im);
    }
}

// ---------------------------------------------------------------------------
// Kernel 2: per-column complex DFT along y, fftshift, fused phase shift and
// CTF pre-multiply. Writes F4[b,h,x] = (cf*re, cf*im, cf*cf, 0).
// ---------------------------------------------------------------------------
__global__ void __launch_bounds__(256) col_fft_phase_kernel(const float2* __restrict__ F1,
                                                            const float* __restrict__ ctf,
                                                            const float* __restrict__ hwShiftAngs,
                                                            float4* __restrict__ F4) {
    const int col = blockIdx.x;            // b*WR + x
    const int b   = col / WR;
    const int x   = col - b * WR;
    const int t   = threadIdx.x;
    __shared__ float2 xin[D];
    __shared__ float2 tw[D];

    xin[t] = F1[((size_t)b * D + t) * WR + x];
    float s, c;
    sincospif(-(float)t * (1.0f / 128.0f), &s, &c);
    tw[t] = make_float2(c, s);
    __syncthreads();

    float re = 0.f, im = 0.f;
    #pragma unroll 4
    for (int y = 0; y < D; ++y) {
        const int m = (t * y) & (D - 1);
        const float2 v = xin[y];                 // broadcast
        const float2 w = tw[m];
        re += v.x * w.x - v.y * w.y;
        im += v.x * w.y + v.y * w.x;
    }

    const int   h  = (t + D / 2) & (D - 1);      // fftshift along y
    const float ky = (float)(h - D / 2);
    const float sy = hwShiftAngs[b * 2 + 0];
    const float sx = hwShiftAngs[b * 2 + 1];
    const float ph = -2.0f * (ky * sy + (float)x * sx) * (1.0f / (float)D);
    float ps, pc;
    sincospif(ph, &ps, &pc);
    const float ore = re * pc - im * ps;
    const float oim = re * ps + im * pc;

    const size_t o = (size_t)(b * D + h) * WR + x;
    const float  cf = ctf[o];
    F4[o] = make_float4(cf * ore, cf * oim, cf * cf, 0.f);
}

// ---------------------------------------------------------------------------
// Kernel 3: tiled GATHER. One block per 16x4x4 voxel tile. Wave 0 culls the
// 64 particles against the tile bounds and compacts survivors into LDS
// (ballot-compaction, deterministic). Each thread then gathers its voxel's
// contributions from only the active particles. Inner candidate logic is
// identical (same fp expressions) to the verified round-2 kernel.
// ---------------------------------------------------------------------------
#define TX 16
#define TY 4
#define TZ 4

__global__ void __launch_bounds__(256) gather_kernel(const float4* __restrict__ F4,
                                                     const float* __restrict__ rotMats,
                                                     float* __restrict__ out) {
    __shared__ float aR[B][12];
    __shared__ int   aBase[B];
    __shared__ int   na_s;

    const int t  = threadIdx.x;
    const int x0 = blockIdx.x * TX;
    const int y0 = blockIdx.y * TY;
    const int z0 = blockIdx.z * TZ;

    // tile center (centered coords) and per-axis half extents (7.5, 1.5, 1.5)
    const float cx = (float)x0 + 7.5f;
    const float cy = (float)y0 + 1.5f - 128.f;
    const float cz = (float)z0 + 1.5f - 128.f;

    if (t < 64) {                       // wave 0: particle culling + compaction
        const float* R = rotMats + t * 9;
        const float R0 = R[0], R1 = R[1], R2 = R[2];
        const float R3 = R[3], R4 = R[4], R5 = R[5];
        const float R6 = R[6], R7 = R[7], R8 = R[8];
        // q = R^T v
        const float qzc = R0 * cz + R3 * cy + R6 * cx;
        const float qyc = R1 * cz + R4 * cy + R7 * cx;
        const float qxc = R2 * cz + R5 * cy + R8 * cx;
        const float mz = SQRT3 + 1.5f * fabsf(R0) + 1.5f * fabsf(R3) + 7.5f * fabsf(R6);
        const float my = 130.f  + 1.5f * fabsf(R1) + 1.5f * fabsf(R4) + 7.5f * fabsf(R7);
        const float mx = 130.f  + 1.5f * fabsf(R2) + 1.5f * fabsf(R5) + 7.5f * fabsf(R8);
        const bool pass = (fabsf(qzc) < mz) & (fabsf(qyc) < my) & (fabsf(qxc) < mx);
        const unsigned long long m = __ballot(pass);
        if (t == 0) na_s = (int)__popcll(m);
        if (pass) {
            const int a = (int)__popcll(m & ((1ull << t) - 1ull));
            aR[a][0] = R0; aR[a][1] = R3; aR[a][2]  = R6;   // col z
            aR[a][4] = R1; aR[a][5] = R4; aR[a][6]  = R7;   // col y
            aR[a][8] = R2; aR[a][9] = R5; aR[a][10] = R8;   // col x
            aBase[a] = t * D * WR;
        }
    }
    __syncthreads();

    const int x = x0 + (t & 15);
    const int y = y0 + ((t >> 4) & 3);
    const int z = z0 + (t >> 6);
    if (x >= WR) return;               // only in the last x-tile; no barriers below

    const float vx = (float)x;
    const float vy = (float)(y - 128);
    const float vz = (float)(z - 128);

    float nre = 0.f, nim = 0.f, wv = 0.f, cv = 0.f;
    const int na = na_s;

    for (int a = 0; a < na; ++a) {
        const float* Rb = aR[a];
        const float qz = Rb[0] * vz + Rb[1] * vy + Rb[2] * vx;
        if (qz * qz >= 3.0f) continue;
        const float R1 = Rb[4], R4 = Rb[5], R7 = Rb[6];
        const float R2 = Rb[8], R5 = Rb[9], R8 = Rb[10];
        const float qy = R1 * vz + R4 * vy + R7 * vx;
        const float qx = R2 * vz + R5 * vy + R8 * vx;
        const int base = aBase[a];

        #pragma unroll
        for (int fi = 0; fi < 2; ++fi) {
            const float fs = fi ? -1.f : 1.f;
            const float ty = fi ? -qy : qy;
            const float tx = fi ? -qx : qx;
            int ky0 = (int)ceilf(ty - SQRT3);  ky0 = max(ky0, -D / 2);
            int ky1 = (int)floorf(ty + SQRT3); ky1 = min(ky1, D / 2 - 1);
            int kx0 = (int)ceilf(tx - SQRT3);  kx0 = max(kx0, 0);
            int kx1 = (int)floorf(tx + SQRT3); kx1 = min(kx1, WR - 1);
            if (ky0 > ky1 || kx0 > kx1) continue;

            for (int ky = ky0; ky <= ky1; ++ky) {
                const float kyf = (float)ky;
                const float sz = R1 * kyf;
                const float sy = R4 * kyf;
                const float sx = R7 * kyf;     // R7*ky (partial rx)
                const int rowb = base + (ky + D / 2) * WR;
                for (int kx = kx0; kx <= kx1; ++kx) {
                    const float kxf = (float)kx;
                    const float rx = fmaf(R8, kxf, sx);      // matches scatter expr
                    if ((rx < 0.f) != (fi == 1)) continue;   // fold membership
                    const float dz_ = fs * fmaf(R2, kxf, sz) - vz;
                    const float az  = fabsf(dz_); if (az >= 1.f) continue;
                    const float dy_ = fs * fmaf(R5, kxf, sy) - vy;
                    const float ay  = fabsf(dy_); if (ay >= 1.f) continue;
                    const float dx_ = fs * rx - vx;
                    const float ax  = fabsf(dx_); if (ax >= 1.f) continue;
                    const float w = (1.f - az) * (1.f - ay) * (1.f - ax);
                    const float4 v = F4[rowb + kx];
                    nre = fmaf(w, v.x, nre);
                    nim = fmaf(w, fi ? -v.y : v.y, nim);
                    wv += w;
                    cv  = fmaf(w, v.z, cv);
                }
            }
        }
    }

    const long idx = (long)z * (D * WR) + (long)y * WR + x;
    out[idx]          = nre;
    out[PL + idx]     = nim;
    out[2 * PL + idx] = wv;
    out[3 * PL + idx] = cv;
}

// ---------------------------------------------------------------------------
extern "C" void kernel_launch(void* const* d_in, const int* in_sizes, int n_in,
                              void* d_out, int out_size, void* d_ws, size_t ws_size,
                              hipStream_t stream) {
    const float* imgs    = (const float*)d_in[0];   // [B, D, D]
    const float* ctf     = (const float*)d_in[1];   // [B, D, WR]
    const float* rotMats = (const float*)d_in[2];   // [B, 3, 3]
    const float* hw      = (const float*)d_in[3];   // [B, 2]
    float* out = (float*)d_out;                     // [4, D, D, WR]

    float2* F1 = (float2*)d_ws;                                   // [B,D,WR] complex (16.9 MB)
    float4* F4 = (float4*)((char*)d_ws + (size_t)B * D * WR * 8); // [B,D,WR] float4 (33.8 MB)

    row_rfft_kernel<<<B * D, 256, 0, stream>>>(imgs, F1);
    col_fft_phase_kernel<<<B * WR, 256, 0, stream>>>(F1, ctf, hw, F4);

    dim3 grid((WR + TX - 1) / TX, D / TY, D / TZ);   // 9 x 64 x 64
    gather_kernel<<<grid, 256, 0, stream>>>(F4, rotMats, out);
}

// Round 4
// 546.717 us; speedup vs baseline: 6.2148x; 1.3562x over previous
//
#include <hip/hip_runtime.h>

#define D   256
#define WR  129          // D/2 + 1
#define B   64
static constexpr long PL = (long)D * D * WR;   // one output plane: 8,454,144 floats
#define SQRT3 1.7320509f

// ===========================================================================
// Radix-2 Stockham FFT, 256-point, one wave (64 lanes) per transform,
// 4 transforms per 256-thread block, LDS ping-pong X<->Y. After 8 stages the
// natural-order result is back in X. Twiddles: one 128-entry table tw256[j] =
// exp(-2*pi*i*j/256) serves every stage via index pm = u & ~(s-1).
// ===========================================================================

// ---------------------------------------------------------------------------
// Kernel 1: row rfft. Packs rows (2rp, 2rp+1) as one complex signal, FFTs,
// untangles to 129 bins, writes transposed F1T[b][k][y] (float2), with the
// (k, y-pair) pair stored as one float4 (16B contiguous).
// Grid: B*D/2/4 = 2048 blocks.
// ---------------------------------------------------------------------------
__global__ void __launch_bounds__(256) row_fft_kernel(const float* __restrict__ imgs,
                                                      float2* __restrict__ F1T) {
    __shared__ float2 Xs[4][D];
    __shared__ float2 Ys[4][D];
    __shared__ float2 tws[128];

    const int t = threadIdx.x;
    const int f = t >> 6;          // transform id within block
    const int r = t & 63;          // lane within transform
    const int blk = blockIdx.x;
    const int b   = blk >> 5;              // 32 blocks per image
    const int rp  = ((blk & 31) << 2) + f; // row pair: rows 2rp, 2rp+1

    if (t < 128) {
        float s, c;
        sincospif(-(float)t * (1.0f / 128.0f), &s, &c);
        tws[t] = make_float2(c, s);
    }

    // load: z[n] = row0[n] + i*row1[n], conflict-free stride-64 pattern
    {
        const float* r0 = imgs + ((size_t)(b * D + 2 * rp)) * D;
        const float* r1 = r0 + D;
        #pragma unroll
        for (int j = 0; j < 4; ++j) {
            const int n = r + 64 * j;
            Xs[f][n] = make_float2(r0[n], r1[n]);
        }
    }
    __syncthreads();

    float2* Xf = Xs[f];
    float2* Yf = Ys[f];
    #pragma unroll
    for (int st = 0; st < 8; ++st) {
        float2* src = (st & 1) ? Yf : Xf;
        float2* dst = (st & 1) ? Xf : Yf;
        const int sB = 1 << st;
        #pragma unroll
        for (int hh = 0; hh < 2; ++hh) {
            const int u  = r + 64 * hh;
            const int pm = u & ~(sB - 1);
            const float2 a  = src[u];
            const float2 bv = src[u + 128];
            const float2 w  = tws[pm];
            const float dx = a.x - bv.x, dy = a.y - bv.y;
            const int o = u + pm;
            dst[o]      = make_float2(a.x + bv.x, a.y + bv.y);
            dst[o + sB] = make_float2(dx * w.x - dy * w.y, dx * w.y + dy * w.x);
        }
        __syncthreads();
    }
    // result in Xf, natural order

    // untangle real pair + transposed store: F1T[(b*129+k)*256 + {2rp,2rp+1}]
    for (int k = r; k <= 128; k += 64) {
        const float2 zk = Xf[k];
        const float2 zm = Xf[(256 - k) & 255];
        // Fe = 0.5(zk + conj(zm)); Fo = -0.5i(zk - conj(zm))
        const float4 o4 = make_float4(0.5f * (zk.x + zm.x), 0.5f * (zk.y - zm.y),
                                      0.5f * (zk.y + zm.y), -0.5f * (zk.x - zm.x));
        *(float4*)&F1T[((size_t)(b * WR + k)) * D + 2 * rp] = o4;
    }
}

// ---------------------------------------------------------------------------
// Kernel 2: column FFT over y for each (b,x), + fftshift + phase + CTF.
// Reads F1T[b][x][y] (contiguous), writes F4[b][h][x] (gather layout).
// Grid: B*WR/4 = 2064 blocks.
// ---------------------------------------------------------------------------
__global__ void __launch_bounds__(256) col_fft_kernel(const float2* __restrict__ F1T,
                                                      const float* __restrict__ ctf,
                                                      const float* __restrict__ hwShiftAngs,
                                                      float4* __restrict__ F4) {
    __shared__ float2 Xs[4][D];
    __shared__ float2 Ys[4][D];
    __shared__ float2 tws[128];

    const int t = threadIdx.x;
    const int f = t >> 6;
    const int r = t & 63;
    const int c = blockIdx.x * 4 + f;   // b*129 + x
    const int b = c / WR;
    const int x = c - b * WR;

    if (t < 128) {
        float s, cc;
        sincospif(-(float)t * (1.0f / 128.0f), &s, &cc);
        tws[t] = make_float2(cc, s);
    }

    {
        const float2* src = F1T + (size_t)c * D;
        #pragma unroll
        for (int j = 0; j < 4; ++j) {
            const int n = r + 64 * j;
            Xs[f][n] = src[n];
        }
    }
    __syncthreads();

    float2* Xf = Xs[f];
    float2* Yf = Ys[f];
    #pragma unroll
    for (int st = 0; st < 8; ++st) {
        float2* src = (st & 1) ? Yf : Xf;
        float2* dst = (st & 1) ? Xf : Yf;
        const int sB = 1 << st;
        #pragma unroll
        for (int hh = 0; hh < 2; ++hh) {
            const int u  = r + 64 * hh;
            const int pm = u & ~(sB - 1);
            const float2 a  = src[u];
            const float2 bv = src[u + 128];
            const float2 w  = tws[pm];
            const float dx = a.x - bv.x, dy = a.y - bv.y;
            const int o = u + pm;
            dst[o]      = make_float2(a.x + bv.x, a.y + bv.y);
            dst[o + sB] = make_float2(dx * w.x - dy * w.y, dx * w.y + dy * w.x);
        }
        __syncthreads();
    }

    const float sy = hwShiftAngs[b * 2 + 0];
    const float sx = hwShiftAngs[b * 2 + 1];

    #pragma unroll
    for (int j = 0; j < 4; ++j) {
        const int tt = r + 64 * j;                 // frequency index (pre-shift)
        const int h  = (tt + D / 2) & (D - 1);     // fftshifted row
        const float ky = (float)(h - D / 2);
        const float2 z = Xf[tt];
        const float ph = -2.0f * (ky * sy + (float)x * sx) * (1.0f / (float)D);
        float ps, pc;
        sincospif(ph, &ps, &pc);
        const float ore = z.x * pc - z.y * ps;
        const float oim = z.x * ps + z.y * pc;
        const size_t o = (size_t)(b * D + h) * WR + x;
        const float cf = ctf[o];
        F4[o] = make_float4(cf * ore, cf * oim, cf * cf, 0.f);
    }
}

// ---------------------------------------------------------------------------
// Kernel 3: tiled GATHER — verbatim from the verified round-3 kernel.
// ---------------------------------------------------------------------------
#define TX 16
#define TY 4
#define TZ 4

__global__ void __launch_bounds__(256) gather_kernel(const float4* __restrict__ F4,
                                                     const float* __restrict__ rotMats,
                                                     float* __restrict__ out) {
    __shared__ float aR[B][12];
    __shared__ int   aBase[B];
    __shared__ int   na_s;

    const int t  = threadIdx.x;
    const int x0 = blockIdx.x * TX;
    const int y0 = blockIdx.y * TY;
    const int z0 = blockIdx.z * TZ;

    const float cx = (float)x0 + 7.5f;
    const float cy = (float)y0 + 1.5f - 128.f;
    const float cz = (float)z0 + 1.5f - 128.f;

    if (t < 64) {                       // wave 0: particle culling + compaction
        const float* R = rotMats + t * 9;
        const float R0 = R[0], R1 = R[1], R2 = R[2];
        const float R3 = R[3], R4 = R[4], R5 = R[5];
        const float R6 = R[6], R7 = R[7], R8 = R[8];
        const float qzc = R0 * cz + R3 * cy + R6 * cx;
        const float qyc = R1 * cz + R4 * cy + R7 * cx;
        const float qxc = R2 * cz + R5 * cy + R8 * cx;
        const float mz = SQRT3 + 1.5f * fabsf(R0) + 1.5f * fabsf(R3) + 7.5f * fabsf(R6);
        const float my = 130.f  + 1.5f * fabsf(R1) + 1.5f * fabsf(R4) + 7.5f * fabsf(R7);
        const float mx = 130.f  + 1.5f * fabsf(R2) + 1.5f * fabsf(R5) + 7.5f * fabsf(R8);
        const bool pass = (fabsf(qzc) < mz) & (fabsf(qyc) < my) & (fabsf(qxc) < mx);
        const unsigned long long m = __ballot(pass);
        if (t == 0) na_s = (int)__popcll(m);
        if (pass) {
            const int a = (int)__popcll(m & ((1ull << t) - 1ull));
            aR[a][0] = R0; aR[a][1] = R3; aR[a][2]  = R6;   // col z
            aR[a][4] = R1; aR[a][5] = R4; aR[a][6]  = R7;   // col y
            aR[a][8] = R2; aR[a][9] = R5; aR[a][10] = R8;   // col x
            aBase[a] = t * D * WR;
        }
    }
    __syncthreads();

    const int x = x0 + (t & 15);
    const int y = y0 + ((t >> 4) & 3);
    const int z = z0 + (t >> 6);
    if (x >= WR) return;               // only in the last x-tile; no barriers below

    const float vx = (float)x;
    const float vy = (float)(y - 128);
    const float vz = (float)(z - 128);

    float nre = 0.f, nim = 0.f, wv = 0.f, cv = 0.f;
    const int na = na_s;

    for (int a = 0; a < na; ++a) {
        const float* Rb = aR[a];
        const float qz = Rb[0] * vz + Rb[1] * vy + Rb[2] * vx;
        if (qz * qz >= 3.0f) continue;
        const float R1 = Rb[4], R4 = Rb[5], R7 = Rb[6];
        const float R2 = Rb[8], R5 = Rb[9], R8 = Rb[10];
        const float qy = R1 * vz + R4 * vy + R7 * vx;
        const float qx = R2 * vz + R5 * vy + R8 * vx;
        const int base = aBase[a];

        #pragma unroll
        for (int fi = 0; fi < 2; ++fi) {
            const float fs = fi ? -1.f : 1.f;
            const float ty = fi ? -qy : qy;
            const float tx = fi ? -qx : qx;
            int ky0 = (int)ceilf(ty - SQRT3);  ky0 = max(ky0, -D / 2);
            int ky1 = (int)floorf(ty + SQRT3); ky1 = min(ky1, D / 2 - 1);
            int kx0 = (int)ceilf(tx - SQRT3);  kx0 = max(kx0, 0);
            int kx1 = (int)floorf(tx + SQRT3); kx1 = min(kx1, WR - 1);
            if (ky0 > ky1 || kx0 > kx1) continue;

            for (int ky = ky0; ky <= ky1; ++ky) {
                const float kyf = (float)ky;
                const float sz = R1 * kyf;
                const float sy = R4 * kyf;
                const float sx = R7 * kyf;     // R7*ky (partial rx)
                const int rowb = base + (ky + D / 2) * WR;
                for (int kx = kx0; kx <= kx1; ++kx) {
                    const float kxf = (float)kx;
                    const float rx = fmaf(R8, kxf, sx);      // matches scatter expr
                    if ((rx < 0.f) != (fi == 1)) continue;   // fold membership
                    const float dz_ = fs * fmaf(R2, kxf, sz) - vz;
                    const float az  = fabsf(dz_); if (az >= 1.f) continue;
                    const float dy_ = fs * fmaf(R5, kxf, sy) - vy;
                    const float ay  = fabsf(dy_); if (ay >= 1.f) continue;
                    const float dx_ = fs * rx - vx;
                    const float ax  = fabsf(dx_); if (ax >= 1.f) continue;
                    const float w = (1.f - az) * (1.f - ay) * (1.f - ax);
                    const float4 v = F4[rowb + kx];
                    nre = fmaf(w, v.x, nre);
                    nim = fmaf(w, fi ? -v.y : v.y, nim);
                    wv += w;
                    cv  = fmaf(w, v.z, cv);
                }
            }
        }
    }

    const long idx = (long)z * (D * WR) + (long)y * WR + x;
    out[idx]          = nre;
    out[PL + idx]     = nim;
    out[2 * PL + idx] = wv;
    out[3 * PL + idx] = cv;
}

// ---------------------------------------------------------------------------
extern "C" void kernel_launch(void* const* d_in, const int* in_sizes, int n_in,
                              void* d_out, int out_size, void* d_ws, size_t ws_size,
                              hipStream_t stream) {
    const float* imgs    = (const float*)d_in[0];   // [B, D, D]
    const float* ctf     = (const float*)d_in[1];   // [B, D, WR]
    const float* rotMats = (const float*)d_in[2];   // [B, 3, 3]
    const float* hw      = (const float*)d_in[3];   // [B, 2]
    float* out = (float*)d_out;                     // [4, D, D, WR]

    float2* F1T = (float2*)d_ws;                                   // [B,WR,D] complex (16.9 MB)
    float4* F4  = (float4*)((char*)d_ws + (size_t)B * D * WR * 8); // [B,D,WR] float4 (33.8 MB)

    row_fft_kernel<<<B * D / 2 / 4, 256, 0, stream>>>(imgs, F1T);
    col_fft_kernel<<<B * WR / 4, 256, 0, stream>>>(F1T, ctf, hw, F4);

    dim3 grid((WR + TX - 1) / TX, D / TY, D / TZ);   // 9 x 64 x 64
    gather_kernel<<<grid, 256, 0, stream>>>(F4, rotMats, out);
}